// Round 2
// baseline (757.726 us; speedup 1.0000x reference)
//
#include <hip/hip_runtime.h>
#include <math.h>

#define B 32
#define S 4096
#define H 1024
#define NCHUNK 32                         // pass-1 blocks per batch
#define ROWS_PER_BLOCK (S / NCHUNK)       // 128
#define ROWS_PER_WAVE (ROWS_PER_BLOCK/4)  // 32
#define PSTRIDE 1040                      // 1024 c + m + l, padded to 16B mult

__device__ __forceinline__ float dot4(float4 a, float4 b) {
    return fmaf(a.x, b.x, fmaf(a.y, b.y, fmaf(a.z, b.z, a.w * b.w)));
}

// Pass 1: fused scores + online softmax + weighted context accumulation.
// One wave owns 32 contiguous s-rows, processed 2 rows/iter with a
// double-buffered prefetch (next 2 rows' loads in flight while computing).
__global__ __launch_bounds__(256) void attn_pass1(
    const float* __restrict__ dec, const float* __restrict__ enc,
    float* __restrict__ scores, float* __restrict__ part)
{
    const int blk   = blockIdx.x;
    const int b     = blk / NCHUNK;
    const int chunk = blk % NCHUNK;
    const int lane  = threadIdx.x & 63;
    const int w     = threadIdx.x >> 6;

    const float4* dsp = (const float4*)(dec + (size_t)b * H);
    float4 dsv[4];
#pragma unroll
    for (int q = 0; q < 4; ++q) dsv[q] = dsp[q * 64 + lane];

    float m = -INFINITY, l = 0.f;
    float4 accq[4];
#pragma unroll
    for (int q = 0; q < 4; ++q) accq[q] = make_float4(0.f, 0.f, 0.f, 0.f);

    const int row0 = chunk * ROWS_PER_BLOCK + w * ROWS_PER_WAVE;
    const float4* base = (const float4*)(enc + ((size_t)b * S + row0) * H);

    // buf[parity][row-in-pair][quarter]; row stride in float4 = H/4 = 256
    float4 buf[2][2][4];
#pragma unroll
    for (int q = 0; q < 4; ++q) {
        buf[0][0][q] = base[q * 64 + lane];
        buf[0][1][q] = base[256 + q * 64 + lane];
    }

#pragma unroll
    for (int rr = 0; rr < ROWS_PER_WAVE; rr += 2) {
        const int pc = (rr >> 1) & 1;
        const int pn = pc ^ 1;
        if (rr + 2 < ROWS_PER_WAVE) {           // compile-time (full unroll)
            const float4* nb = base + (size_t)(rr + 2) * 256;
#pragma unroll
            for (int q = 0; q < 4; ++q) {
                buf[pn][0][q] = nb[q * 64 + lane];
                buf[pn][1][q] = nb[256 + q * 64 + lane];
            }
        }

        // two independent dot chains
        float s0 = (dot4(buf[pc][0][0], dsv[0]) + dot4(buf[pc][0][1], dsv[1]))
                 + (dot4(buf[pc][0][2], dsv[2]) + dot4(buf[pc][0][3], dsv[3]));
        float s1 = (dot4(buf[pc][1][0], dsv[0]) + dot4(buf[pc][1][1], dsv[1]))
                 + (dot4(buf[pc][1][2], dsv[2]) + dot4(buf[pc][1][3], dsv[3]));

        // interleaved 64-lane butterflies (2 independent DS chains)
#pragma unroll
        for (int d = 32; d >= 1; d >>= 1) {
            s0 += __shfl_xor(s0, d);
            s1 += __shfl_xor(s1, d);
        }

        if (lane == 0) {
            float2 sv = make_float2(s0, s1);
            *(float2*)&scores[(size_t)b * S + row0 + rr] = sv;
        }

        // branchless online-softmax update for both rows
        const float mn = fmaxf(m, fmaxf(s0, s1));
        const float a  = __expf(m - mn);        // exp(-inf)=0 on first iter
        const float p0 = __expf(s0 - mn);
        const float p1 = __expf(s1 - mn);
        m = mn;
        l = fmaf(l, a, p0 + p1);
#pragma unroll
        for (int q = 0; q < 4; ++q) {
            const float4 e0 = buf[pc][0][q];
            const float4 e1 = buf[pc][1][q];
            accq[q].x = fmaf(p1, e1.x, fmaf(p0, e0.x, accq[q].x * a));
            accq[q].y = fmaf(p1, e1.y, fmaf(p0, e0.y, accq[q].y * a));
            accq[q].z = fmaf(p1, e1.z, fmaf(p0, e0.z, accq[q].z * a));
            accq[q].w = fmaf(p1, e1.w, fmaf(p0, e0.w, accq[q].w * a));
        }
    }

    // Combine the 4 wave partials -> one block partial
    __shared__ float sm[4], sl[4];
    __shared__ float sc[4][1024];
    if (lane == 0) { sm[w] = m; sl[w] = l; }
#pragma unroll
    for (int q = 0; q < 4; ++q)
        *(float4*)&sc[w][(q * 64 + lane) * 4] = accq[q];
    __syncthreads();

    const float M  = fmaxf(fmaxf(sm[0], sm[1]), fmaxf(sm[2], sm[3]));
    const float al0 = __expf(sm[0] - M), al1 = __expf(sm[1] - M);
    const float al2 = __expf(sm[2] - M), al3 = __expf(sm[3] - M);
    const float Lb = sl[0]*al0 + sl[1]*al1 + sl[2]*al2 + sl[3]*al3;

    const int t = threadIdx.x;
    const float4 c0 = *(const float4*)&sc[0][t * 4];
    const float4 c1 = *(const float4*)&sc[1][t * 4];
    const float4 c2 = *(const float4*)&sc[2][t * 4];
    const float4 c3 = *(const float4*)&sc[3][t * 4];
    float4 cp;
    cp.x = c0.x*al0 + c1.x*al1 + c2.x*al2 + c3.x*al3;
    cp.y = c0.y*al0 + c1.y*al1 + c2.y*al2 + c3.y*al3;
    cp.z = c0.z*al0 + c1.z*al1 + c2.z*al2 + c3.z*al3;
    cp.w = c0.w*al0 + c1.w*al1 + c2.w*al2 + c3.w*al3;

    float* pb = part + (size_t)blk * PSTRIDE;
    *(float4*)&pb[t * 4] = cp;
    if (t == 0) { pb[1024] = M; pb[1025] = Lb; }
}

// Pass 2: reduce the 32 per-block partials of each batch to global (M, L),
// then emit context (h-slice) and attn (s-slice).
__global__ __launch_bounds__(256) void attn_pass2(
    const float* __restrict__ scores, const float* __restrict__ part,
    float* __restrict__ out)
{
    const int b = blockIdx.x >> 2;
    const int j = blockIdx.x & 3;
    const int t = threadIdx.x;
    const float* pbase = part + (size_t)b * NCHUNK * PSTRIDE;

    float M = -INFINITY;
    for (int i = 0; i < NCHUNK; ++i)
        M = fmaxf(M, pbase[i * PSTRIDE + 1024]);
    float L = 0.f;
    for (int i = 0; i < NCHUNK; ++i)
        L += pbase[i * PSTRIDE + 1025] * __expf(pbase[i * PSTRIDE + 1024] - M);
    const float invL = 1.f / L;

    // context slice: h = j*256 + t
    const int h = j * 256 + t;
    float acc = 0.f;
    for (int i = 0; i < NCHUNK; ++i)
        acc = fmaf(__expf(pbase[i * PSTRIDE + 1024] - M),
                   pbase[i * PSTRIDE + h], acc);
    out[(size_t)b * H + h] = acc * invL;

    // attn slice: s in [j*1024, (j+1)*1024)
    float* attn_out = out + (size_t)B * H;
    for (int k = 0; k < 4; ++k) {
        const int s = j * 1024 + k * 256 + t;
        attn_out[(size_t)b * S + s] =
            __expf(scores[(size_t)b * S + s] - M) * invL;
    }
}

extern "C" void kernel_launch(void* const* d_in, const int* in_sizes, int n_in,
                              void* d_out, int out_size, void* d_ws, size_t ws_size,
                              hipStream_t stream) {
    const float* dec = (const float*)d_in[0];   // (32, 1024)
    const float* enc = (const float*)d_in[1];   // (32, 4096, 1024)
    float* out = (float*)d_out;                 // context(32*1024) ++ attn(32*4096)
    float* ws  = (float*)d_ws;
    float* scores = ws;                         // B*S floats
    float* part   = ws + (size_t)B * S;         // B*NCHUNK*PSTRIDE floats (~4.3 MB)

    attn_pass1<<<B * NCHUNK, 256, 0, stream>>>(dec, enc, scores, part);
    attn_pass2<<<B * 4, 256, 0, stream>>>(scores, part, out);
}

// Round 3
// 690.084 us; speedup vs baseline: 1.0980x; 1.0980x over previous
//
#include <hip/hip_runtime.h>
#include <math.h>

#define B 32
#define S 4096
#define H 1024
#define NCHUNK 32                          // pass-1 blocks per batch
#define ROWS_PER_BLOCK (S / NCHUNK)        // 128
#define ROWS_PER_WAVE  (ROWS_PER_BLOCK/4)  // 32
#define PPB 4                              // partials per block (one per wave)
#define NPART_PER_B (NCHUNK * PPB)         // 128
#define PSTRIDE 1040                       // 1024 c + m + l, padded to 16B mult

typedef float v4 __attribute__((ext_vector_type(4)));

__device__ __forceinline__ float dot4v(v4 a, v4 b) {
    return fmaf(a.x, b.x, fmaf(a.y, b.y, fmaf(a.z, b.z, a.w * b.w)));
}

// Pass 1: fused scores + online softmax + weighted context accumulation.
// One wave owns 32 contiguous s-rows. Single-row lookahead (cur/nxt) keeps
// one 4KB row-load in flight per wave while the dot/shfl/update chain runs.
// #pragma unroll 1 pins VGPR pressure (~100) -> 4 waves/SIMD.
// Each wave writes its own (c[1024], m, l) partial -- no LDS, no barrier.
__global__ __launch_bounds__(256) void attn_pass1(
    const float* __restrict__ dec, const float* __restrict__ enc,
    float* __restrict__ scores, float* __restrict__ part)
{
    const int blk   = blockIdx.x;
    const int b     = blk / NCHUNK;
    const int chunk = blk % NCHUNK;
    const int lane  = threadIdx.x & 63;
    const int w     = threadIdx.x >> 6;

    const v4* dsp = (const v4*)(dec + (size_t)b * H);
    v4 dsv[4];
#pragma unroll
    for (int q = 0; q < 4; ++q) dsv[q] = dsp[q * 64 + lane];

    float m = -INFINITY, l = 0.f;
    v4 accq[4];
#pragma unroll
    for (int q = 0; q < 4; ++q) accq[q] = (v4)(0.f);

    const int row0 = chunk * ROWS_PER_BLOCK + w * ROWS_PER_WAVE;
    const v4* base = (const v4*)(enc + ((size_t)b * S + row0) * H);
    float* srow = scores + (size_t)b * S + row0;

    v4 cur[4], nxt[4];
#pragma unroll
    for (int q = 0; q < 4; ++q)
        cur[q] = __builtin_nontemporal_load(&base[q * 64 + lane]);

#pragma unroll 1
    for (int r = 0; r < ROWS_PER_WAVE; ++r) {
        if (r + 1 < ROWS_PER_WAVE) {       // issue next row's loads FIRST
            const v4* nb = base + (size_t)(r + 1) * (H / 4);
#pragma unroll
            for (int q = 0; q < 4; ++q)
                nxt[q] = __builtin_nontemporal_load(&nb[q * 64 + lane]);
        }

        float s = (dot4v(cur[0], dsv[0]) + dot4v(cur[1], dsv[1]))
                + (dot4v(cur[2], dsv[2]) + dot4v(cur[3], dsv[3]));
#pragma unroll
        for (int d = 32; d >= 1; d >>= 1) s += __shfl_xor(s, d);
        if (lane == 0) srow[r] = s;

        // branchless online-softmax update
        const float mn = fmaxf(m, s);
        const float a  = __expf(m - mn);   // exp(-inf)=0 on first iter
        const float p  = __expf(s - mn);
        m = mn;
        l = fmaf(l, a, p);
#pragma unroll
        for (int q = 0; q < 4; ++q) {
            accq[q].x = fmaf(p, cur[q].x, accq[q].x * a);
            accq[q].y = fmaf(p, cur[q].y, accq[q].y * a);
            accq[q].z = fmaf(p, cur[q].z, accq[q].z * a);
            accq[q].w = fmaf(p, cur[q].w, accq[q].w * a);
            cur[q] = nxt[q];
        }
    }

    // per-wave partial: c[1024] + (m, l)
    float* pb = part + ((size_t)blk * PPB + w) * PSTRIDE;
#pragma unroll
    for (int q = 0; q < 4; ++q)
        *(v4*)&pb[(q * 64 + lane) * 4] = accq[q];
    if (lane == 0) { pb[1024] = m; pb[1025] = l; }
}

// Pass 2: reduce the 128 per-wave partials of each batch to global (M, L),
// then emit context (h-slice) and attn (s-slice).
__global__ __launch_bounds__(256) void attn_pass2(
    const float* __restrict__ scores, const float* __restrict__ part,
    float* __restrict__ out)
{
    const int b = blockIdx.x >> 2;
    const int j = blockIdx.x & 3;
    const int t = threadIdx.x;
    const float* pbase = part + (size_t)b * NPART_PER_B * PSTRIDE;

    float M = -INFINITY;
    for (int i = 0; i < NPART_PER_B; ++i)
        M = fmaxf(M, pbase[i * PSTRIDE + 1024]);
    float L = 0.f;
    for (int i = 0; i < NPART_PER_B; ++i)
        L += pbase[i * PSTRIDE + 1025] * __expf(pbase[i * PSTRIDE + 1024] - M);
    const float invL = 1.f / L;

    // context slice: h = j*256 + t
    const int h = j * 256 + t;
    float acc = 0.f;
    for (int i = 0; i < NPART_PER_B; ++i)
        acc = fmaf(__expf(pbase[i * PSTRIDE + 1024] - M),
                   pbase[i * PSTRIDE + h], acc);
    out[(size_t)b * H + h] = acc * invL;

    // attn slice: s in [j*1024, (j+1)*1024)
    float* attn_out = out + (size_t)B * H;
    for (int k = 0; k < 4; ++k) {
        const int s = j * 1024 + k * 256 + t;
        attn_out[(size_t)b * S + s] =
            __expf(scores[(size_t)b * S + s] - M) * invL;
    }
}

extern "C" void kernel_launch(void* const* d_in, const int* in_sizes, int n_in,
                              void* d_out, int out_size, void* d_ws, size_t ws_size,
                              hipStream_t stream) {
    const float* dec = (const float*)d_in[0];   // (32, 1024)
    const float* enc = (const float*)d_in[1];   // (32, 4096, 1024)
    float* out = (float*)d_out;                 // context(32*1024) ++ attn(32*4096)
    float* ws  = (float*)d_ws;
    float* scores = ws;                         // B*S floats (512 KB)
    float* part   = ws + (size_t)B * S;         // 4096 partials * PSTRIDE (~17 MB)

    attn_pass1<<<B * NCHUNK, 256, 0, stream>>>(dec, enc, scores, part);
    attn_pass2<<<B * 4, 256, 0, stream>>>(scores, part, out);
}